// Round 6
// baseline (5543.791 us; speedup 1.0000x reference)
//
#include <hip/hip_runtime.h>

#define D 512
#define C 1024
#define BM 128
#define BN 128
#define NCHUNK 8    // C / BN
#define KSTEPS 16   // D / 32
#define NBLK_CU 8192

typedef _Float16 f16x8 __attribute__((ext_vector_type(8)));
typedef float f32x4 __attribute__((ext_vector_type(4)));

__device__ __forceinline__ void gll16(const void* g, void* l) {
    __builtin_amdgcn_global_load_lds(
        (const __attribute__((address_space(1))) void*)g,
        (__attribute__((address_space(3))) void*)l, 16, 0, 0);
}

// lexicographic (score, index) insert into sorted top-3
__device__ __forceinline__ void ins3(float s, int i,
                                     float& s1, int& i1, float& s2, int& i2,
                                     float& s3, int& i3) {
    if (s < s1 || (s == s1 && i < i1)) { s3 = s2; i3 = i2; s2 = s1; i2 = i1; s1 = s; i1 = i; }
    else if (s < s2 || (s == s2 && i < i2)) { s3 = s2; i3 = i2; s2 = s; i2 = i; }
    else if (s < s3 || (s == s3 && i < i3)) { s3 = s; i3 = i; }
}

// ---- ||c||^2 for all Q*C codes (fp32)
__global__ __launch_bounds__(256) void cbnorm_kernel(const float* __restrict__ cb,
                                                     float* __restrict__ cbn) {
    int code = blockIdx.x * 4 + (threadIdx.x >> 6);
    int lane = threadIdx.x & 63;
    const float* row = cb + (size_t)code * D;
    float4 a = *(const float4*)(row + lane * 8);
    float4 b = *(const float4*)(row + lane * 8 + 4);
    float s = a.x*a.x + a.y*a.y + a.z*a.z + a.w*a.w
            + b.x*b.x + b.y*b.y + b.z*b.z + b.w*b.w;
    #pragma unroll
    for (int off = 32; off > 0; off >>= 1) s += __shfl_down(s, off, 64);
    if (lane == 0) cbn[code] = s;
}

// ---- f16 plane of codebooks in MFMA-fragment tile order (written once, read-only after).
// uint4 index t = ((q*8+cc)*16+ks)*512 + tile*64 + ksub*16 + col
__global__ __launch_bounds__(256) void cb_split_kernel(const float* __restrict__ cbs,
                                                       uint4* __restrict__ hi_plane) {
    int t = blockIdx.x * 256 + threadIdx.x;
    int rg = t >> 9;
    int u  = t & 511;
    int q  = rg >> 7;
    int cc = (rg >> 4) & 7;
    int ks = rg & 15;
    int tile = u >> 6;
    int ksub = (u >> 4) & 3;
    int col  = u & 15;
    int code = cc * 128 + tile * 16 + col;
    int d0   = ks * 32 + ksub * 8;
    const float* src = cbs + ((size_t)q * C + code) * D + d0;
    float4 v0 = *(const float4*)src;
    float4 v1 = *(const float4*)(src + 4);
    float xv[8] = {v0.x, v0.y, v0.z, v0.w, v1.x, v1.y, v1.z, v1.w};
    f16x8 h;
    #pragma unroll
    for (int e = 0; e < 8; ++e) h[e] = (_Float16)xv[e];
    hi_plane[t] = __builtin_bit_cast(uint4, h);
}

// ---- 1-pass f16 MFMA distance GEMM, in-kernel A conversion, fused per-wave top-3.
__global__ __launch_bounds__(256, 4) void vq_mfma_step(
    const float* __restrict__ rin,     // fp32 residual (or x at q=0)
    const uint4* __restrict__ bhq,     // f16 plane of this codebook
    const float* __restrict__ cbnq,    // [C] norms
    float4*      __restrict__ partial) // [P][16]: (s1,s2,s3, packed i1|i2<<10|i3<<20)
{
    __shared__ uint4 SH[2][2][512];    // 0=A 1=B, 32 KiB
    const int tid  = threadIdx.x;
    const int lane = tid & 63;
    const int wv   = tid >> 6;
    const int wm   = wv >> 1, wn = wv & 1;
    const int bm   = blockIdx.x & 255;   // stride-256 cc siblings share XCD/L2
    const int cc   = blockIdx.x >> 8;
    const int bp   = bm * BM;

    f32x4 acc[4][4];
    #pragma unroll
    for (int i = 0; i < 4; ++i)
        #pragma unroll
        for (int j = 0; j < 4; ++j) acc[i][j] = (f32x4){0.f, 0.f, 0.f, 0.f};

    auto STAGE = [&](int buf, int ks) {
        const uint4* bh = bhq + (size_t)(cc * KSTEPS + ks) * 512;
        gll16(bh + tid,       &SH[buf][1][tid]);
        gll16(bh + tid + 256, &SH[buf][1][tid + 256]);
        #pragma unroll
        for (int it = 0; it < 2; ++it) {
            int oct  = tid + it * 256;
            int row  = ((oct >> 6) << 4) + (oct & 15);
            int ksub = (oct >> 4) & 3;
            const float* src = rin + (size_t)(bp + row) * D + ks * 32 + ksub * 8;
            float4 v0 = *(const float4*)src;
            float4 v1 = *(const float4*)(src + 4);
            float xv[8] = {v0.x, v0.y, v0.z, v0.w, v1.x, v1.y, v1.z, v1.w};
            f16x8 h;
            #pragma unroll
            for (int e = 0; e < 8; ++e) h[e] = (_Float16)xv[e];
            SH[buf][0][oct] = __builtin_bit_cast(uint4, h);
        }
    };

    STAGE(0, 0);
    int buf = 0;
    for (int ks = 0; ks < KSTEPS; ++ks) {
        __syncthreads();
        if (ks + 1 < KSTEPS) STAGE(buf ^ 1, ks + 1);
        f16x8 ah[4], bh[4];
        #pragma unroll
        for (int mt = 0; mt < 4; ++mt)
            ah[mt] = __builtin_bit_cast(f16x8, SH[buf][0][(wm * 4 + mt) * 64 + lane]);
        #pragma unroll
        for (int nt = 0; nt < 4; ++nt)
            bh[nt] = __builtin_bit_cast(f16x8, SH[buf][1][(wn * 4 + nt) * 64 + lane]);
        #pragma unroll
        for (int mt = 0; mt < 4; ++mt)
            #pragma unroll
            for (int nt = 0; nt < 4; ++nt)
                acc[mt][nt] = __builtin_amdgcn_mfma_f32_16x16x32_f16(ah[mt], bh[nt], acc[mt][nt], 0, 0, 0);
        buf ^= 1;
    }

    // epilogue: score = ||c||^2 - 2 r.c ; per-wave top-3 over its 64 codes
    const int colbase = cc * BN;
    float cbn_l[4];
    int   ci_l[4];
    #pragma unroll
    for (int nt = 0; nt < 4; ++nt) {
        ci_l[nt]  = colbase + (wn * 4 + nt) * 16 + (lane & 15);
        cbn_l[nt] = cbnq[ci_l[nt]];
    }
    #pragma unroll
    for (int mt = 0; mt < 4; ++mt) {
        #pragma unroll
        for (int r = 0; r < 4; ++r) {
            float s1 = 3.4e38f, s2 = 3.4e38f, s3 = 3.4e38f;
            int i1 = 1023, i2 = 1023, i3 = 1023;
            #pragma unroll
            for (int nt = 0; nt < 4; ++nt) {
                float s = fmaf(-2.f, acc[mt][nt][r], cbn_l[nt]);
                ins3(s, ci_l[nt], s1, i1, s2, i2, s3, i3);
            }
            #pragma unroll
            for (int m = 1; m < 16; m <<= 1) {
                float o1 = __shfl_xor(s1, m, 64); int oi1 = __shfl_xor(i1, m, 64);
                float o2 = __shfl_xor(s2, m, 64); int oi2 = __shfl_xor(i2, m, 64);
                float o3 = __shfl_xor(s3, m, 64); int oi3 = __shfl_xor(i3, m, 64);
                ins3(o1, oi1, s1, i1, s2, i2, s3, i3);
                ins3(o2, oi2, s1, i1, s2, i2, s3, i3);
                ins3(o3, oi3, s1, i1, s2, i2, s3, i3);
            }
            if ((lane & 15) == 0) {
                int row = bp + wm * 64 + mt * 16 + (lane >> 4) * 4 + r;
                unsigned pk = (unsigned)i1 | ((unsigned)i2 << 10) | ((unsigned)i3 << 20);
                partial[(size_t)row * 16 + cc * 2 + wn] =
                    make_float4(s1, s2, s3, __builtin_bit_cast(float, pk));
            }
        }
    }
}

// ---- merge 16 top-3s -> global top-3; fp64 rescore all 3 (exact argmin);
//      residual update + per-block loss partial. No atomics.
__global__ __launch_bounds__(256) void combine_update(
    const float* __restrict__ rin, float* __restrict__ rout,
    const float* __restrict__ cbq,
    const float4* __restrict__ partial,
    float* __restrict__ idx_out, float* __restrict__ blockloss,
    int q, int nq)
{
    __shared__ float wls[4];
    const int lane = threadIdx.x & 63;
    const int wv   = threadIdx.x >> 6;
    const int p    = blockIdx.x * 4 + wv;

    float s1 = 3.4e38f, s2 = 3.4e38f, s3 = 3.4e38f;
    int i1 = 1023, i2 = 1023, i3 = 1023;
    if (lane < 16) {
        float4 v = partial[(size_t)p * 16 + lane];
        unsigned pk = __builtin_bit_cast(unsigned, v.w);
        s1 = v.x; s2 = v.y; s3 = v.z;
        i1 = pk & 1023; i2 = (pk >> 10) & 1023; i3 = (pk >> 20) & 1023;
    }
    #pragma unroll
    for (int m = 1; m < 16; m <<= 1) {
        float o1 = __shfl_xor(s1, m, 64); int oi1 = __shfl_xor(i1, m, 64);
        float o2 = __shfl_xor(s2, m, 64); int oi2 = __shfl_xor(i2, m, 64);
        float o3 = __shfl_xor(s3, m, 64); int oi3 = __shfl_xor(i3, m, 64);
        ins3(o1, oi1, s1, i1, s2, i2, s3, i3);
        ins3(o2, oi2, s1, i1, s2, i2, s3, i3);
        ins3(o3, oi3, s1, i1, s2, i2, s3, i3);
    }
    i1 = __shfl(i1, 0, 64);
    i2 = __shfl(i2, 0, 64);
    i3 = __shfl(i3, 0, 64);

    const float* rrow = rin + (size_t)p * D;
    float4 r0 = *(const float4*)(rrow + lane * 8);
    float4 r1 = *(const float4*)(rrow + lane * 8 + 4);
    const float* c1 = cbq + (size_t)i1 * D;
    const float* c2 = cbq + (size_t)i2 * D;
    const float* c3 = cbq + (size_t)i3 * D;
    float4 a0 = *(const float4*)(c1 + lane * 8), a1 = *(const float4*)(c1 + lane * 8 + 4);
    float4 b0 = *(const float4*)(c2 + lane * 8), b1 = *(const float4*)(c2 + lane * 8 + 4);
    float4 g0 = *(const float4*)(c3 + lane * 8), g1 = *(const float4*)(c3 + lane * 8 + 4);
    float ra[8] = {r0.x, r0.y, r0.z, r0.w, r1.x, r1.y, r1.z, r1.w};
    float aa[8] = {a0.x, a0.y, a0.z, a0.w, a1.x, a1.y, a1.z, a1.w};
    float bb[8] = {b0.x, b0.y, b0.z, b0.w, b1.x, b1.y, b1.z, b1.w};
    float gg[8] = {g0.x, g0.y, g0.z, g0.w, g1.x, g1.y, g1.z, g1.w};

    double d1 = 0.0, d2 = 0.0, d3 = 0.0;
    #pragma unroll
    for (int e = 0; e < 8; ++e) {
        double rr = (double)ra[e];
        double av = (double)aa[e], bv = (double)bb[e], gv = (double)gg[e];
        d1 += av * av - 2.0 * rr * av;
        d2 += bv * bv - 2.0 * rr * bv;
        d3 += gv * gv - 2.0 * rr * gv;
    }
    #pragma unroll
    for (int m = 32; m > 0; m >>= 1) {
        d1 += __shfl_xor(d1, m, 64);
        d2 += __shfl_xor(d2, m, 64);
        d3 += __shfl_xor(d3, m, 64);
    }
    int    fi = i1;
    double fd = d1;
    if (d2 < fd || (d2 == fd && i2 < fi)) { fd = d2; fi = i2; }
    if (d3 < fd || (d3 == fd && i3 < fi)) { fd = d3; fi = i3; }
    if (lane == 0) idx_out[(size_t)p * nq + q] = (float)fi;

    float nsum = 0.f;
    float nv[8];
    #pragma unroll
    for (int e = 0; e < 8; ++e) {
        float cv = (fi == i1) ? aa[e] : ((fi == i2) ? bb[e] : gg[e]);
        nv[e] = ra[e] - cv;
        nsum = fmaf(nv[e], nv[e], nsum);
    }
    float4 w0 = {nv[0], nv[1], nv[2], nv[3]};
    float4 w1 = {nv[4], nv[5], nv[6], nv[7]};
    *(float4*)(rout + (size_t)p * D + lane * 8)     = w0;
    *(float4*)(rout + (size_t)p * D + lane * 8 + 4) = w1;
    #pragma unroll
    for (int off = 32; off > 0; off >>= 1) nsum += __shfl_down(nsum, off, 64);
    if (lane == 0) wls[wv] = nsum;
    __syncthreads();
    if (threadIdx.x == 0)
        blockloss[(size_t)q * NBLK_CU + blockIdx.x] = wls[0] + wls[1] + wls[2] + wls[3];
}

// ---- quantized = x - final_residual (in place); blocks 0..nq-1 reduce losses.
__global__ __launch_bounds__(256) void finalize_kernel(
    const float* __restrict__ x, float* __restrict__ outq,
    const float* __restrict__ blockloss,
    float* __restrict__ losses, float invPD, int n4, int nq)
{
    if (blockIdx.x < (unsigned)nq) {
        __shared__ float wls[4];
        int q = blockIdx.x;
        float s = 0.f;
        for (int i = threadIdx.x; i < NBLK_CU; i += 256)
            s += blockloss[(size_t)q * NBLK_CU + i];
        #pragma unroll
        for (int off = 32; off > 0; off >>= 1) s += __shfl_down(s, off, 64);
        if ((threadIdx.x & 63) == 0) wls[threadIdx.x >> 6] = s;
        __syncthreads();
        if (threadIdx.x == 0) {
            float vq = (wls[0] + wls[1] + wls[2] + wls[3]) * invPD;
            losses[q] = vq;
            losses[nq + q] = 0.25f * vq;
        }
    }
    int stride = gridDim.x * blockDim.x;
    for (int i = blockIdx.x * blockDim.x + threadIdx.x; i < n4; i += stride) {
        float4 xv = ((const float4*)x)[i];
        float4 rv = ((float4*)outq)[i];
        float4 qv;
        qv.x = xv.x - rv.x;
        qv.y = xv.y - rv.y;
        qv.z = xv.z - rv.z;
        qv.w = xv.w - rv.w;
        ((float4*)outq)[i] = qv;
    }
}

extern "C" void kernel_launch(void* const* d_in, const int* in_sizes, int n_in,
                              void* d_out, int out_size, void* d_ws, size_t ws_size,
                              hipStream_t stream)
{
    const float* x   = (const float*)d_in[0];
    const float* cbs = (const float*)d_in[1];
    const int PD = in_sizes[0];                // 16777216
    const int P  = PD / D;                     // 32768
    const int nq = in_sizes[1] / (C * D);      // 8

    float* out     = (float*)d_out;
    float* resid   = out;
    float* idx_out = out + (size_t)PD;
    float* losses  = idx_out + (size_t)P * nq;

    // ws: [0,8M) cb_hi | [8M,+32K) cbn | partial 8M | blockloss 256K  (~17 MB)
    char* wsb = (char*)d_ws;
    uint4*  cb_hi     = (uint4*)wsb;
    float*  cbn       = (float*)(wsb + 8388608);
    float4* partial   = (float4*)(wsb + 8421376);
    float*  blockloss = (float*)(wsb + 16809984);

    cbnorm_kernel<<<nq * C / 4, 256, 0, stream>>>(cbs, cbn);
    cb_split_kernel<<<nq * C * D / 8 / 256, 256, 0, stream>>>(cbs, cb_hi);

    for (int q = 0; q < nq; ++q) {
        const float* rin = (q == 0) ? x : resid;
        vq_mfma_step<<<(P / BM) * NCHUNK, 256, 0, stream>>>(
            rin, cb_hi + (size_t)q * 65536, cbn + (size_t)q * C, partial);
        combine_update<<<P / 4, 256, 0, stream>>>(
            rin, resid, cbs + (size_t)q * C * D, partial,
            idx_out, blockloss, q, nq);
    }
    finalize_kernel<<<2048, 256, 0, stream>>>(x, out, blockloss, losses,
                                              1.f / (float)PD, PD / 4, nq);
}

// Round 7
// 5543.767 us; speedup vs baseline: 1.0000x; 1.0000x over previous
//
#include <hip/hip_runtime.h>

#define D 512
#define C 1024
#define BM 128
#define BN 128
#define NCHUNK 8    // C / BN
#define KSTEPS 16   // D / 32
#define NBLK_CU 8192

typedef _Float16 f16x8 __attribute__((ext_vector_type(8)));
typedef float f32x4 __attribute__((ext_vector_type(4)));

__device__ __forceinline__ void gll16(const void* g, void* l) {
    __builtin_amdgcn_global_load_lds(
        (const __attribute__((address_space(1))) void*)g,
        (__attribute__((address_space(3))) void*)l, 16, 0, 0);
}

// lexicographic (score, index) insert into sorted top-3
__device__ __forceinline__ void ins3(float s, int i,
                                     float& s1, int& i1, float& s2, int& i2,
                                     float& s3, int& i3) {
    if (s < s1 || (s == s1 && i < i1)) { s3 = s2; i3 = i2; s2 = s1; i2 = i1; s1 = s; i1 = i; }
    else if (s < s2 || (s == s2 && i < i2)) { s3 = s2; i3 = i2; s2 = s; i2 = i; }
    else if (s < s3 || (s == s3 && i < i3)) { s3 = s; i3 = i; }
}

// ---- ||c||^2 for all Q*C codes (fp32)
__global__ __launch_bounds__(256) void cbnorm_kernel(const float* __restrict__ cb,
                                                     float* __restrict__ cbn) {
    int code = blockIdx.x * 4 + (threadIdx.x >> 6);
    int lane = threadIdx.x & 63;
    const float* row = cb + (size_t)code * D;
    float4 a = *(const float4*)(row + lane * 8);
    float4 b = *(const float4*)(row + lane * 8 + 4);
    float s = a.x*a.x + a.y*a.y + a.z*a.z + a.w*a.w
            + b.x*b.x + b.y*b.y + b.z*b.z + b.w*b.w;
    #pragma unroll
    for (int off = 32; off > 0; off >>= 1) s += __shfl_down(s, off, 64);
    if (lane == 0) cbn[code] = s;
}

// ---- f16 plane of codebooks in MFMA-fragment tile order (written once, read-only after).
// uint4 index t = ((q*8+cc)*16+ks)*512 + tile*64 + ksub*16 + col
__global__ __launch_bounds__(256) void cb_split_kernel(const float* __restrict__ cbs,
                                                       uint4* __restrict__ hi_plane) {
    int t = blockIdx.x * 256 + threadIdx.x;
    int rg = t >> 9;
    int u  = t & 511;
    int q  = rg >> 7;
    int cc = (rg >> 4) & 7;
    int ks = rg & 15;
    int tile = u >> 6;
    int ksub = (u >> 4) & 3;
    int col  = u & 15;
    int code = cc * 128 + tile * 16 + col;
    int d0   = ks * 32 + ksub * 8;
    const float* src = cbs + ((size_t)q * C + code) * D + d0;
    float4 v0 = *(const float4*)src;
    float4 v1 = *(const float4*)(src + 4);
    float xv[8] = {v0.x, v0.y, v0.z, v0.w, v1.x, v1.y, v1.z, v1.w};
    f16x8 h;
    #pragma unroll
    for (int e = 0; e < 8; ++e) h[e] = (_Float16)xv[e];
    hi_plane[t] = __builtin_bit_cast(uint4, h);
}

// ---- 1-pass f16 MFMA distance GEMM, in-kernel A conversion, fused per-wave top-3.
// NOTE: launch_bounds (256,2) — (256,4) capped VGPR at 64 and spilled acc to
// scratch (round 6: WRITE_SIZE 8.6->36MB, MfmaUtil 22->2%, 3.2x slower).
__global__ __launch_bounds__(256, 2) void vq_mfma_step(
    const float* __restrict__ rin,     // fp32 residual (or x at q=0)
    const uint4* __restrict__ bhq,     // f16 plane of this codebook
    const float* __restrict__ cbnq,    // [C] norms
    float4*      __restrict__ partial) // [P][16]: (s1,s2,s3, packed i1|i2<<10|i3<<20)
{
    __shared__ uint4 SH[2][2][512];    // 0=A 1=B, 32 KiB
    const int tid  = threadIdx.x;
    const int lane = tid & 63;
    const int wv   = tid >> 6;
    const int wm   = wv >> 1, wn = wv & 1;
    const int bm   = blockIdx.x & 255;   // stride-256 cc siblings share XCD/L2
    const int cc   = blockIdx.x >> 8;
    const int bp   = bm * BM;

    f32x4 acc[4][4];
    #pragma unroll
    for (int i = 0; i < 4; ++i)
        #pragma unroll
        for (int j = 0; j < 4; ++j) acc[i][j] = (f32x4){0.f, 0.f, 0.f, 0.f};

    auto STAGE = [&](int buf, int ks) {
        const uint4* bh = bhq + (size_t)(cc * KSTEPS + ks) * 512;
        gll16(bh + tid,       &SH[buf][1][tid]);
        gll16(bh + tid + 256, &SH[buf][1][tid + 256]);
        #pragma unroll
        for (int it = 0; it < 2; ++it) {
            int oct  = tid + it * 256;
            int row  = ((oct >> 6) << 4) + (oct & 15);
            int ksub = (oct >> 4) & 3;
            const float* src = rin + (size_t)(bp + row) * D + ks * 32 + ksub * 8;
            float4 v0 = *(const float4*)src;
            float4 v1 = *(const float4*)(src + 4);
            float xv[8] = {v0.x, v0.y, v0.z, v0.w, v1.x, v1.y, v1.z, v1.w};
            f16x8 h;
            #pragma unroll
            for (int e = 0; e < 8; ++e) h[e] = (_Float16)xv[e];
            SH[buf][0][oct] = __builtin_bit_cast(uint4, h);
        }
    };

    STAGE(0, 0);
    int buf = 0;
    for (int ks = 0; ks < KSTEPS; ++ks) {
        __syncthreads();
        if (ks + 1 < KSTEPS) STAGE(buf ^ 1, ks + 1);
        f16x8 ah[4], bh[4];
        #pragma unroll
        for (int mt = 0; mt < 4; ++mt)
            ah[mt] = __builtin_bit_cast(f16x8, SH[buf][0][(wm * 4 + mt) * 64 + lane]);
        #pragma unroll
        for (int nt = 0; nt < 4; ++nt)
            bh[nt] = __builtin_bit_cast(f16x8, SH[buf][1][(wn * 4 + nt) * 64 + lane]);
        #pragma unroll
        for (int mt = 0; mt < 4; ++mt)
            #pragma unroll
            for (int nt = 0; nt < 4; ++nt)
                acc[mt][nt] = __builtin_amdgcn_mfma_f32_16x16x32_f16(ah[mt], bh[nt], acc[mt][nt], 0, 0, 0);
        buf ^= 1;
    }

    // epilogue: score = ||c||^2 - 2 r.c ; per-wave top-3 over its 64 codes
    const int colbase = cc * BN;
    float cbn_l[4];
    int   ci_l[4];
    #pragma unroll
    for (int nt = 0; nt < 4; ++nt) {
        ci_l[nt]  = colbase + (wn * 4 + nt) * 16 + (lane & 15);
        cbn_l[nt] = cbnq[ci_l[nt]];
    }
    #pragma unroll
    for (int mt = 0; mt < 4; ++mt) {
        #pragma unroll
        for (int r = 0; r < 4; ++r) {
            float s1 = 3.4e38f, s2 = 3.4e38f, s3 = 3.4e38f;
            int i1 = 1023, i2 = 1023, i3 = 1023;
            #pragma unroll
            for (int nt = 0; nt < 4; ++nt) {
                float s = fmaf(-2.f, acc[mt][nt][r], cbn_l[nt]);
                ins3(s, ci_l[nt], s1, i1, s2, i2, s3, i3);
            }
            #pragma unroll
            for (int m = 1; m < 16; m <<= 1) {
                float o1 = __shfl_xor(s1, m, 64); int oi1 = __shfl_xor(i1, m, 64);
                float o2 = __shfl_xor(s2, m, 64); int oi2 = __shfl_xor(i2, m, 64);
                float o3 = __shfl_xor(s3, m, 64); int oi3 = __shfl_xor(i3, m, 64);
                ins3(o1, oi1, s1, i1, s2, i2, s3, i3);
                ins3(o2, oi2, s1, i1, s2, i2, s3, i3);
                ins3(o3, oi3, s1, i1, s2, i2, s3, i3);
            }
            if ((lane & 15) == 0) {
                int row = bp + wm * 64 + mt * 16 + (lane >> 4) * 4 + r;
                unsigned pk = (unsigned)i1 | ((unsigned)i2 << 10) | ((unsigned)i3 << 20);
                partial[(size_t)row * 16 + cc * 2 + wn] =
                    make_float4(s1, s2, s3, __builtin_bit_cast(float, pk));
            }
        }
    }
}

// ---- merge 16 top-3s -> global top-3; fp64 rescore all 3 (exact argmin);
//      residual update + per-block loss partial. No atomics.
__global__ __launch_bounds__(256) void combine_update(
    const float* __restrict__ rin, float* __restrict__ rout,
    const float* __restrict__ cbq,
    const float4* __restrict__ partial,
    float* __restrict__ idx_out, float* __restrict__ blockloss,
    int q, int nq)
{
    __shared__ float wls[4];
    const int lane = threadIdx.x & 63;
    const int wv   = threadIdx.x >> 6;
    const int p    = blockIdx.x * 4 + wv;

    float s1 = 3.4e38f, s2 = 3.4e38f, s3 = 3.4e38f;
    int i1 = 1023, i2 = 1023, i3 = 1023;
    if (lane < 16) {
        float4 v = partial[(size_t)p * 16 + lane];
        unsigned pk = __builtin_bit_cast(unsigned, v.w);
        s1 = v.x; s2 = v.y; s3 = v.z;
        i1 = pk & 1023; i2 = (pk >> 10) & 1023; i3 = (pk >> 20) & 1023;
    }
    #pragma unroll
    for (int m = 1; m < 16; m <<= 1) {
        float o1 = __shfl_xor(s1, m, 64); int oi1 = __shfl_xor(i1, m, 64);
        float o2 = __shfl_xor(s2, m, 64); int oi2 = __shfl_xor(i2, m, 64);
        float o3 = __shfl_xor(s3, m, 64); int oi3 = __shfl_xor(i3, m, 64);
        ins3(o1, oi1, s1, i1, s2, i2, s3, i3);
        ins3(o2, oi2, s1, i1, s2, i2, s3, i3);
        ins3(o3, oi3, s1, i1, s2, i2, s3, i3);
    }
    i1 = __shfl(i1, 0, 64);
    i2 = __shfl(i2, 0, 64);
    i3 = __shfl(i3, 0, 64);

    const float* rrow = rin + (size_t)p * D;
    float4 r0 = *(const float4*)(rrow + lane * 8);
    float4 r1 = *(const float4*)(rrow + lane * 8 + 4);
    const float* c1 = cbq + (size_t)i1 * D;
    const float* c2 = cbq + (size_t)i2 * D;
    const float* c3 = cbq + (size_t)i3 * D;
    float4 a0 = *(const float4*)(c1 + lane * 8), a1 = *(const float4*)(c1 + lane * 8 + 4);
    float4 b0 = *(const float4*)(c2 + lane * 8), b1 = *(const float4*)(c2 + lane * 8 + 4);
    float4 g0 = *(const float4*)(c3 + lane * 8), g1 = *(const float4*)(c3 + lane * 8 + 4);
    float ra[8] = {r0.x, r0.y, r0.z, r0.w, r1.x, r1.y, r1.z, r1.w};
    float aa[8] = {a0.x, a0.y, a0.z, a0.w, a1.x, a1.y, a1.z, a1.w};
    float bb[8] = {b0.x, b0.y, b0.z, b0.w, b1.x, b1.y, b1.z, b1.w};
    float gg[8] = {g0.x, g0.y, g0.z, g0.w, g1.x, g1.y, g1.z, g1.w};

    double d1 = 0.0, d2 = 0.0, d3 = 0.0;
    #pragma unroll
    for (int e = 0; e < 8; ++e) {
        double rr = (double)ra[e];
        double av = (double)aa[e], bv = (double)bb[e], gv = (double)gg[e];
        d1 += av * av - 2.0 * rr * av;
        d2 += bv * bv - 2.0 * rr * bv;
        d3 += gv * gv - 2.0 * rr * gv;
    }
    #pragma unroll
    for (int m = 32; m > 0; m >>= 1) {
        d1 += __shfl_xor(d1, m, 64);
        d2 += __shfl_xor(d2, m, 64);
        d3 += __shfl_xor(d3, m, 64);
    }
    int    fi = i1;
    double fd = d1;
    if (d2 < fd || (d2 == fd && i2 < fi)) { fd = d2; fi = i2; }
    if (d3 < fd || (d3 == fd && i3 < fi)) { fd = d3; fi = i3; }
    if (lane == 0) idx_out[(size_t)p * nq + q] = (float)fi;

    float nsum = 0.f;
    float nv[8];
    #pragma unroll
    for (int e = 0; e < 8; ++e) {
        float cv = (fi == i1) ? aa[e] : ((fi == i2) ? bb[e] : gg[e]);
        nv[e] = ra[e] - cv;
        nsum = fmaf(nv[e], nv[e], nsum);
    }
    float4 w0 = {nv[0], nv[1], nv[2], nv[3]};
    float4 w1 = {nv[4], nv[5], nv[6], nv[7]};
    *(float4*)(rout + (size_t)p * D + lane * 8)     = w0;
    *(float4*)(rout + (size_t)p * D + lane * 8 + 4) = w1;
    #pragma unroll
    for (int off = 32; off > 0; off >>= 1) nsum += __shfl_down(nsum, off, 64);
    if (lane == 0) wls[wv] = nsum;
    __syncthreads();
    if (threadIdx.x == 0)
        blockloss[(size_t)q * NBLK_CU + blockIdx.x] = wls[0] + wls[1] + wls[2] + wls[3];
}

// ---- quantized = x - final_residual (in place); blocks 0..nq-1 reduce losses.
__global__ __launch_bounds__(256) void finalize_kernel(
    const float* __restrict__ x, float* __restrict__ outq,
    const float* __restrict__ blockloss,
    float* __restrict__ losses, float invPD, int n4, int nq)
{
    if (blockIdx.x < (unsigned)nq) {
        __shared__ float wls[4];
        int q = blockIdx.x;
        float s = 0.f;
        for (int i = threadIdx.x; i < NBLK_CU; i += 256)
            s += blockloss[(size_t)q * NBLK_CU + i];
        #pragma unroll
        for (int off = 32; off > 0; off >>= 1) s += __shfl_down(s, off, 64);
        if ((threadIdx.x & 63) == 0) wls[threadIdx.x >> 6] = s;
        __syncthreads();
        if (threadIdx.x == 0) {
            float vq = (wls[0] + wls[1] + wls[2] + wls[3]) * invPD;
            losses[q] = vq;
            losses[nq + q] = 0.25f * vq;
        }
    }
    int stride = gridDim.x * blockDim.x;
    for (int i = blockIdx.x * blockDim.x + threadIdx.x; i < n4; i += stride) {
        float4 xv = ((const float4*)x)[i];
        float4 rv = ((float4*)outq)[i];
        float4 qv;
        qv.x = xv.x - rv.x;
        qv.y = xv.y - rv.y;
        qv.z = xv.z - rv.z;
        qv.w = xv.w - rv.w;
        ((float4*)outq)[i] = qv;
    }
}

extern "C" void kernel_launch(void* const* d_in, const int* in_sizes, int n_in,
                              void* d_out, int out_size, void* d_ws, size_t ws_size,
                              hipStream_t stream)
{
    const float* x   = (const float*)d_in[0];
    const float* cbs = (const float*)d_in[1];
    const int PD = in_sizes[0];                // 16777216
    const int P  = PD / D;                     // 32768
    const int nq = in_sizes[1] / (C * D);      // 8

    float* out     = (float*)d_out;
    float* resid   = out;
    float* idx_out = out + (size_t)PD;
    float* losses  = idx_out + (size_t)P * nq;

    // ws: [0,8M) cb_hi | [8M,+32K) cbn | partial 8M | blockloss 256K  (~17 MB)
    char* wsb = (char*)d_ws;
    uint4*  cb_hi     = (uint4*)wsb;
    float*  cbn       = (float*)(wsb + 8388608);
    float4* partial   = (float4*)(wsb + 8421376);
    float*  blockloss = (float*)(wsb + 16809984);

    cbnorm_kernel<<<nq * C / 4, 256, 0, stream>>>(cbs, cbn);
    cb_split_kernel<<<nq * C * D / 8 / 256, 256, 0, stream>>>(cbs, cb_hi);

    for (int q = 0; q < nq; ++q) {
        const float* rin = (q == 0) ? x : resid;
        vq_mfma_step<<<(P / BM) * NCHUNK, 256, 0, stream>>>(
            rin, cb_hi + (size_t)q * 65536, cbn + (size_t)q * C, partial);
        combine_update<<<P / 4, 256, 0, stream>>>(
            rin, resid, cbs + (size_t)q * C * D, partial,
            idx_out, blockloss, q, nq);
    }
    finalize_kernel<<<2048, 256, 0, stream>>>(x, out, blockloss, losses,
                                              1.f / (float)PD, PD / 4, nq);
}

// Round 8
// 2665.834 us; speedup vs baseline: 2.0796x; 2.0796x over previous
//
#include <hip/hip_runtime.h>

#define D 512
#define C 1024
#define BMF 64       // rows per block (fused kernel)
#define KSTEPS 16    // D / 32
#define NCC 8        // C / 128

typedef _Float16 f16x8 __attribute__((ext_vector_type(8)));
typedef float f32x4 __attribute__((ext_vector_type(4)));

// lexicographic (score, index) insert into sorted top-3
__device__ __forceinline__ void ins3(float s, int i,
                                     float& s1, int& i1, float& s2, int& i2,
                                     float& s3, int& i3) {
    if (s < s1 || (s == s1 && i < i1)) { s3 = s2; i3 = i2; s2 = s1; i2 = i1; s1 = s; i1 = i; }
    else if (s < s2 || (s == s2 && i < i2)) { s3 = s2; i3 = i2; s2 = s; i2 = i; }
    else if (s < s3 || (s == s3 && i < i3)) { s3 = s; i3 = i; }
}

// ---- ||c||^2 for all Q*C codes (fp32)
__global__ __launch_bounds__(256) void cbnorm_kernel(const float* __restrict__ cb,
                                                     float* __restrict__ cbn) {
    int code = blockIdx.x * 4 + (threadIdx.x >> 6);
    int lane = threadIdx.x & 63;
    const float* row = cb + (size_t)code * D;
    float4 a = *(const float4*)(row + lane * 8);
    float4 b = *(const float4*)(row + lane * 8 + 4);
    float s = a.x*a.x + a.y*a.y + a.z*a.z + a.w*a.w
            + b.x*b.x + b.y*b.y + b.z*b.z + b.w*b.w;
    #pragma unroll
    for (int off = 32; off > 0; off >>= 1) s += __shfl_down(s, off, 64);
    if (lane == 0) cbn[code] = s;
}

// ---- f16 plane of codebooks in MFMA-fragment tile order (written once per call).
// uint4 index t = ((q*8+cc)*16+ks)*512 + tile*64 + ksub*16 + col
__global__ __launch_bounds__(256) void cb_split_kernel(const float* __restrict__ cbs,
                                                       uint4* __restrict__ hi_plane) {
    int t = blockIdx.x * 256 + threadIdx.x;
    int rg = t >> 9;
    int u  = t & 511;
    int q  = rg >> 7;
    int cc = (rg >> 4) & 7;
    int ks = rg & 15;
    int tile = u >> 6;
    int ksub = (u >> 4) & 3;
    int col  = u & 15;
    int code = cc * 128 + tile * 16 + col;
    int d0   = ks * 32 + ksub * 8;
    const float* src = cbs + ((size_t)q * C + code) * D + d0;
    float4 v0 = *(const float4*)src;
    float4 v1 = *(const float4*)(src + 4);
    float xv[8] = {v0.x, v0.y, v0.z, v0.w, v1.x, v1.y, v1.z, v1.w};
    f16x8 h;
    #pragma unroll
    for (int e = 0; e < 8; ++e) h[e] = (_Float16)xv[e];
    hi_plane[t] = __builtin_bit_cast(uint4, h);
}

// ---- fused VQ step: A-tile resident in LDS, cc-loop in-block, running top-3,
//      fp64 rescore + residual update + loss, all in one kernel. 512 thr, 8 waves.
__global__ __launch_bounds__(512, 4) void vq_fused_step(
    const float* __restrict__ rin,
    float*       __restrict__ rout,
    const uint4* __restrict__ bplane,  // [128 chunks][512] uint4 (1 MB), fragment order
    const float* __restrict__ cbq,     // fp32 codebook [C][D]
    const float* __restrict__ cbnq,    // [C]
    float* __restrict__ idx_out,
    float* __restrict__ blockloss,     // [nblk] for this q
    int q, int nq)
{
    __shared__ uint4  A_lds[4096];     // 64 KiB: 16 ks x 256 (4 tiles x 64)
    __shared__ uint4  B_lds[512];      // 8 KiB: one 128-code x 32-k chunk
    __shared__ float4 rowtop[BMF][2];  // per-row top-3 per col-half
    __shared__ float  wls[8];

    const int tid  = threadIdx.x;
    const int lane = tid & 63;
    const int w    = tid >> 6;         // 0..7
    const int wm   = w >> 1, wn = w & 1;
    const int bp   = blockIdx.x * BMF;

    // ---- stage A: fp32 -> f16 fragments (one time). lane covers d = lane*8..+8
    {
        const int ks = lane >> 2, ksub = lane & 3;
        #pragma unroll
        for (int j = 0; j < 8; ++j) {
            int row = w * 8 + j;
            const float* src = rin + (size_t)(bp + row) * D + lane * 8;
            float4 v0 = *(const float4*)src;
            float4 v1 = *(const float4*)(src + 4);
            float xv[8] = {v0.x, v0.y, v0.z, v0.w, v1.x, v1.y, v1.z, v1.w};
            f16x8 h;
            #pragma unroll
            for (int e = 0; e < 8; ++e) h[e] = (_Float16)xv[e];
            int idx = ks * 256 + (row >> 4) * 64 + ksub * 16 + (row & 15);
            A_lds[idx ^ (ks & 7)] = __builtin_bit_cast(uint4, h);  // bank swizzle
        }
    }
    uint4 breg = bplane[tid];                 // chunk 0 -> regs (overlaps A staging)
    __syncthreads();                          // A_lds ready
    B_lds[tid] = breg;
    breg = bplane[512 + tid];                 // prefetch chunk 1
    __syncthreads();                          // B_lds chunk 0 ready

    float S1[4], S2[4], S3[4];
    int   I1[4], I2[4], I3[4];
    #pragma unroll
    for (int r = 0; r < 4; ++r) {
        S1[r] = S2[r] = S3[r] = 3.4e38f;
        I1[r] = I2[r] = I3[r] = 1023;
    }

    for (int cc = 0; cc < NCC; ++cc) {
        f32x4 acc[4];
        #pragma unroll
        for (int nt = 0; nt < 4; ++nt) acc[nt] = (f32x4){0.f, 0.f, 0.f, 0.f};
        for (int ks = 0; ks < KSTEPS; ++ks) {
            int it = cc * KSTEPS + ks;
            int aidx = ks * 256 + wm * 64 + lane;
            f16x8 af = __builtin_bit_cast(f16x8, A_lds[aidx ^ (ks & 7)]);
            f16x8 bf[4];
            #pragma unroll
            for (int nt = 0; nt < 4; ++nt)
                bf[nt] = __builtin_bit_cast(f16x8, B_lds[(wn * 4 + nt) * 64 + lane]);
            #pragma unroll
            for (int nt = 0; nt < 4; ++nt)
                acc[nt] = __builtin_amdgcn_mfma_f32_16x16x32_f16(af, bf[nt], acc[nt], 0, 0, 0);
            __syncthreads();                  // all waves done reading B_lds
            if (it < 127) {
                B_lds[tid] = breg;            // install next chunk
                if (it < 126) breg = bplane[(size_t)(it + 2) * 512 + tid];
            }
            __syncthreads();                  // next chunk visible
        }
        // fold this chunk's scores into running top-3 (codes cc*128 .. +127)
        #pragma unroll
        for (int nt = 0; nt < 4; ++nt) {
            int code = cc * 128 + (wn * 4 + nt) * 16 + (lane & 15);
            float nrm = cbnq[code];
            #pragma unroll
            for (int r = 0; r < 4; ++r) {
                float s = fmaf(-2.f, acc[nt][r], nrm);
                ins3(s, code, S1[r], I1[r], S2[r], I2[r], S3[r], I3[r]);
            }
        }
    }

    // merge across the 16 columns within each lane group
    #pragma unroll
    for (int r = 0; r < 4; ++r) {
        #pragma unroll
        for (int m = 1; m < 16; m <<= 1) {
            float o1 = __shfl_xor(S1[r], m, 64); int oi1 = __shfl_xor(I1[r], m, 64);
            float o2 = __shfl_xor(S2[r], m, 64); int oi2 = __shfl_xor(I2[r], m, 64);
            float o3 = __shfl_xor(S3[r], m, 64); int oi3 = __shfl_xor(I3[r], m, 64);
            ins3(o1, oi1, S1[r], I1[r], S2[r], I2[r], S3[r], I3[r]);
            ins3(o2, oi2, S1[r], I1[r], S2[r], I2[r], S3[r], I3[r]);
            ins3(o3, oi3, S1[r], I1[r], S2[r], I2[r], S3[r], I3[r]);
        }
    }
    if ((lane & 15) == 0) {
        int hi = lane >> 4;
        #pragma unroll
        for (int r = 0; r < 4; ++r) {
            int row = wm * 16 + hi * 4 + r;
            unsigned pk = (unsigned)I1[r] | ((unsigned)I2[r] << 10) | ((unsigned)I3[r] << 20);
            rowtop[row][wn] = make_float4(S1[r], S2[r], S3[r], __builtin_bit_cast(float, pk));
        }
    }
    __syncthreads();

    // ---- per-row: merge halves, fp64 rescore top-3, update residual, loss
    float wsum = 0.f;
    for (int j = 0; j < 8; ++j) {
        int rr = w * 8 + j;
        float4 t0 = rowtop[rr][0];
        float4 t1 = rowtop[rr][1];
        float s1 = 3.4e38f, s2 = 3.4e38f, s3 = 3.4e38f;
        int i1 = 1023, i2 = 1023, i3 = 1023;
        unsigned p0 = __builtin_bit_cast(unsigned, t0.w);
        unsigned p1 = __builtin_bit_cast(unsigned, t1.w);
        ins3(t0.x, (int)(p0 & 1023),         s1, i1, s2, i2, s3, i3);
        ins3(t0.y, (int)((p0 >> 10) & 1023), s1, i1, s2, i2, s3, i3);
        ins3(t0.z, (int)((p0 >> 20) & 1023), s1, i1, s2, i2, s3, i3);
        ins3(t1.x, (int)(p1 & 1023),         s1, i1, s2, i2, s3, i3);
        ins3(t1.y, (int)((p1 >> 10) & 1023), s1, i1, s2, i2, s3, i3);
        ins3(t1.z, (int)((p1 >> 20) & 1023), s1, i1, s2, i2, s3, i3);

        size_t grow = (size_t)(bp + rr);
        const float* rrow = rin + grow * D;
        float4 r0 = *(const float4*)(rrow + lane * 8);
        float4 r1 = *(const float4*)(rrow + lane * 8 + 4);
        const float* c1 = cbq + (size_t)i1 * D;
        const float* c2 = cbq + (size_t)i2 * D;
        const float* c3 = cbq + (size_t)i3 * D;
        float4 a0 = *(const float4*)(c1 + lane * 8), a1 = *(const float4*)(c1 + lane * 8 + 4);
        float4 b0 = *(const float4*)(c2 + lane * 8), b1 = *(const float4*)(c2 + lane * 8 + 4);
        float4 g0 = *(const float4*)(c3 + lane * 8), g1 = *(const float4*)(c3 + lane * 8 + 4);
        float ra[8] = {r0.x, r0.y, r0.z, r0.w, r1.x, r1.y, r1.z, r1.w};
        float aa[8] = {a0.x, a0.y, a0.z, a0.w, a1.x, a1.y, a1.z, a1.w};
        float bb[8] = {b0.x, b0.y, b0.z, b0.w, b1.x, b1.y, b1.z, b1.w};
        float gg[8] = {g0.x, g0.y, g0.z, g0.w, g1.x, g1.y, g1.z, g1.w};

        double d1 = 0.0, d2 = 0.0, d3 = 0.0;
        #pragma unroll
        for (int e = 0; e < 8; ++e) {
            double rv = (double)ra[e];
            double av = (double)aa[e], bv = (double)bb[e], gv = (double)gg[e];
            d1 += av * av - 2.0 * rv * av;
            d2 += bv * bv - 2.0 * rv * bv;
            d3 += gv * gv - 2.0 * rv * gv;
        }
        #pragma unroll
        for (int m = 32; m > 0; m >>= 1) {
            d1 += __shfl_xor(d1, m, 64);
            d2 += __shfl_xor(d2, m, 64);
            d3 += __shfl_xor(d3, m, 64);
        }
        int fi = i1; double fd = d1;
        if (d2 < fd || (d2 == fd && i2 < fi)) { fd = d2; fi = i2; }
        if (d3 < fd || (d3 == fd && i3 < fi)) { fd = d3; fi = i3; }
        if (lane == 0) idx_out[grow * nq + q] = (float)fi;

        float nv[8];
        #pragma unroll
        for (int e = 0; e < 8; ++e) {
            float cv = (fi == i1) ? aa[e] : ((fi == i2) ? bb[e] : gg[e]);
            nv[e] = ra[e] - cv;
            wsum = fmaf(nv[e], nv[e], wsum);
        }
        float4 w0 = {nv[0], nv[1], nv[2], nv[3]};
        float4 w1 = {nv[4], nv[5], nv[6], nv[7]};
        *(float4*)(rout + grow * D + lane * 8)     = w0;
        *(float4*)(rout + grow * D + lane * 8 + 4) = w1;
    }
    #pragma unroll
    for (int off = 32; off > 0; off >>= 1) wsum += __shfl_down(wsum, off, 64);
    if (lane == 0) wls[w] = wsum;
    __syncthreads();
    if (tid == 0) {
        float s = 0.f;
        #pragma unroll
        for (int k = 0; k < 8; ++k) s += wls[k];
        blockloss[blockIdx.x] = s;
    }
}

// ---- quantized = x - final_residual (in place); blocks 0..nq-1 reduce losses.
__global__ __launch_bounds__(256) void finalize_kernel(
    const float* __restrict__ x, float* __restrict__ outq,
    const float* __restrict__ blockloss,
    float* __restrict__ losses, float invPD, int n4, int nq, int nblk)
{
    if (blockIdx.x < (unsigned)nq) {
        __shared__ float wls[4];
        int q = blockIdx.x;
        float s = 0.f;
        for (int i = threadIdx.x; i < nblk; i += 256)
            s += blockloss[(size_t)q * nblk + i];
        #pragma unroll
        for (int off = 32; off > 0; off >>= 1) s += __shfl_down(s, off, 64);
        if ((threadIdx.x & 63) == 0) wls[threadIdx.x >> 6] = s;
        __syncthreads();
        if (threadIdx.x == 0) {
            float vq = (wls[0] + wls[1] + wls[2] + wls[3]) * invPD;
            losses[q] = vq;
            losses[nq + q] = 0.25f * vq;
        }
    }
    int stride = gridDim.x * blockDim.x;
    for (int i = blockIdx.x * blockDim.x + threadIdx.x; i < n4; i += stride) {
        float4 xv = ((const float4*)x)[i];
        float4 rv = ((float4*)outq)[i];
        float4 qv;
        qv.x = xv.x - rv.x;
        qv.y = xv.y - rv.y;
        qv.z = xv.z - rv.z;
        qv.w = xv.w - rv.w;
        ((float4*)outq)[i] = qv;
    }
}

extern "C" void kernel_launch(void* const* d_in, const int* in_sizes, int n_in,
                              void* d_out, int out_size, void* d_ws, size_t ws_size,
                              hipStream_t stream)
{
    const float* x   = (const float*)d_in[0];
    const float* cbs = (const float*)d_in[1];
    const int PD = in_sizes[0];                // 16777216
    const int P  = PD / D;                     // 32768
    const int nq = in_sizes[1] / (C * D);      // 8
    const int nblk = P / BMF;                  // 512

    float* out     = (float*)d_out;
    float* resid   = out;
    float* idx_out = out + (size_t)PD;
    float* losses  = idx_out + (size_t)P * nq;

    // ws: [0, 8M) cb f16 planes | +32KB cbn | +nq*nblk*4 blockloss
    char* wsb = (char*)d_ws;
    uint4* cb_hi     = (uint4*)wsb;
    float* cbn       = (float*)(wsb + 8388608);
    float* blockloss = (float*)(wsb + 8421376);

    cbnorm_kernel<<<nq * C / 4, 256, 0, stream>>>(cbs, cbn);
    cb_split_kernel<<<nq * C * D / 8 / 256, 256, 0, stream>>>(cbs, cb_hi);

    for (int q = 0; q < nq; ++q) {
        const float* rin = (q == 0) ? x : resid;
        vq_fused_step<<<nblk, 512, 0, stream>>>(
            rin, resid,
            cb_hi + (size_t)q * 65536,
            cbs + (size_t)q * C * D,
            cbn + (size_t)q * C,
            idx_out, blockloss + (size_t)q * nblk, q, nq);
    }
    finalize_kernel<<<2048, 256, 0, stream>>>(x, out, blockloss, losses,
                                              1.f / (float)PD, PD / 4, nq, nblk);
}